// Round 1
// baseline (1005.230 us; speedup 1.0000x reference)
//
#include <hip/hip_runtime.h>
#include <math.h>

// LSTM: B=512, T=1000, I=64, H=50, gates 4H=200 (torch order i,f,g,o).
// One block per batch row, 512 threads:
//   tid <  400 : workers. tid -> (u = tid>>3, g = (tid>>1)&3, half = tid&1).
//                Each lane computes HALF of gate (g,u)'s dot product with its
//                57-58 weights held in VGPRs as f32x2 pairs (v_pk_fma_f32).
//                Pair-combine (shfl_xor 1) + butterfly (shfl_xor 2,4) gives
//                every lane of the 8-lane unit-group all 4 activated gates ->
//                cell update fully in-wave, ONE barrier per step.
//   tid >= 448 : loader wave. Depth-2 prefetch of x[t] with raw s_barrier
//                (lgkmcnt-only drain) so the global load stays in flight
//                across the step barrier.

#define HSZ 50
#define ISZ 64
#define TSZ 1000

typedef float f32x2 __attribute__((ext_vector_type(2)));

__device__ __forceinline__ void pkfma(f32x2& acc, f32x2 a, f32x2 b) {
    // acc.x += a.x*b.x; acc.y += a.y*b.y  (one VALU issue)
    asm("v_pk_fma_f32 %0, %1, %2, %0" : "+v"(acc) : "v"(a), "v"(b));
}

// one recurrence step; CUR is a compile-time 0/1 so all LDS addresses fold
#define LSTM_STEP(CUR, TT)                                                    \
  {                                                                           \
    if (tid < 400) {                                                          \
      f32x2 acc2; acc2.x = bias; acc2.y = 0.0f;                               \
      const float4* x4 = (const float4*)(&xs[CUR][half << 5]);                \
      _Pragma("unroll")                                                       \
      for (int i = 0; i < 8; ++i) {                                           \
        float4 v = x4[i];                                                     \
        f32x2 lo = {v.x, v.y};                                                \
        f32x2 hi = {v.z, v.w};                                                \
        pkfma(acc2, lo, wih2[2 * i]);                                         \
        pkfma(acc2, hi, wih2[2 * i + 1]);                                     \
      }                                                                       \
      const float4* h4 = (const float4*)(&hsb[CUR][half * 24]);               \
      _Pragma("unroll")                                                       \
      for (int j = 0; j < 6; ++j) {                                           \
        float4 v = h4[j];                                                     \
        f32x2 lo = {v.x, v.y};                                                \
        f32x2 hi = {v.z, v.w};                                                \
        pkfma(acc2, lo, whh2[2 * j]);                                         \
        pkfma(acc2, hi, whh2[2 * j + 1]);                                     \
      }                                                                       \
      if (half) { /* h[48],h[49] */                                           \
        f32x2 t2 = *(const f32x2*)(&hsb[CUR][48]);                            \
        pkfma(acc2, t2, whh2[12]);                                            \
      }                                                                       \
      float acc = acc2.x + acc2.y;                                            \
      acc += __shfl_xor(acc, 1);            /* both lanes: full preact */     \
      /* activation: sigmoid for i,f,o; tanh(v)=2*sigmoid(2v)-1 for g */      \
      float arg = isg ? (acc + acc) : acc;                                    \
      float e = __expf(-arg);                                                 \
      float s = __fdividef(1.0f, 1.0f + e);                                   \
      float a = isg ? (s + s - 1.0f) : s;                                     \
      /* butterfly: every lane of the 8-lane group gets all 4 gates */        \
      float bb = __shfl_xor(a, 2);                                            \
      float cv = __shfl_xor(a, 4);                                            \
      float dv = __shfl_xor(bb, 4);                                           \
      float xlo = b0 ? bb : a,  xhi = b0 ? a : bb;                            \
      float ylo = b0 ? dv : cv, yhi = b0 ? cv : dv;                           \
      float ig = b1 ? ylo : xlo, fg = b1 ? yhi : xhi;                         \
      float gg = b1 ? xlo : ylo, og = b1 ? xhi : yhi;                         \
      c_reg = fg * c_reg + ig * gg;                                           \
      float ep = __expf(c_reg + c_reg);                                       \
      float th = 1.0f - __fdividef(2.0f, 1.0f + ep);   /* tanh(c) */          \
      if ((tid & 7) == 0) hsb[CUR ^ 1][u] = og * th;                          \
    } else if (tid >= 448) {                                                  \
      if ((TT) + 1 < TSZ) {                                                   \
        xs[CUR ^ 1][lload] = xr; /* waits only the arrived older load */      \
        if ((TT) + 2 < TSZ) xr = xb[(size_t)((TT) + 2) * ISZ + lload];        \
      }                                                                       \
    }                                                                         \
    /* raw barrier: drain LDS only -- loader's global load stays in flight */ \
    asm volatile("s_waitcnt lgkmcnt(0)" ::: "memory");                        \
    __builtin_amdgcn_s_barrier();                                             \
    asm volatile("" ::: "memory");                                            \
    __builtin_amdgcn_sched_barrier(0);                                        \
  }

__global__ __launch_bounds__(512, 4) void lstm_fused(
    const float* __restrict__ x,      // [B, T, I]
    const float* __restrict__ W_ih,   // [4H, I]
    const float* __restrict__ W_hh,   // [4H, H]
    const float* __restrict__ b_ih,   // [4H]
    const float* __restrict__ b_hh,   // [4H]
    const float* __restrict__ W_out,  // [2, H]
    const float* __restrict__ b_out,  // [2]
    float* __restrict__ out)          // [B, 2]
{
    const int b   = blockIdx.x;
    const int tid = threadIdx.x;

    __shared__ __align__(16) float xs[2][ISZ];   // double-buffered x_t
    __shared__ __align__(16) float hsb[2][56];   // double-buffered h (row 224B)

    // worker coordinates
    const int u    = tid >> 3;          // unit [0,50)
    const int g    = (tid >> 1) & 3;    // gate 0=i 1=f 2=g 3=o
    const int half = tid & 1;           // which half of the dot product
    const bool isg = (g == 2);
    const bool b0  = (g & 1) != 0;
    const bool b1  = (g & 2) != 0;

    // per-thread weights as f32x2 pairs (fit VGPRs: ~58 floats/thread)
    f32x2 wih2[16];
    f32x2 whh2[13];
    float bias = 0.0f;
    if (tid < 400) {
        const int r = g * HSZ + u;                 // row in [0,200)
        const float* wi = W_ih + r * ISZ + (half << 5);
        #pragma unroll
        for (int i = 0; i < 16; ++i) wih2[i] = *(const f32x2*)(wi + 2 * i);
        // half 0: h-cols 0..23 ; half 1: h-cols 24..47 (+48,49)
        const float* wh = W_hh + r * HSZ + half * 24;
        #pragma unroll
        for (int j = 0; j < 12; ++j) whh2[j] = *(const f32x2*)(wh + 2 * j);
        if (half) whh2[12] = *(const f32x2*)(wh + 24);   // cols 48,49
        else      { whh2[12].x = 0.0f; whh2[12].y = 0.0f; }
        if (!half) bias = b_ih[r] + b_hh[r];
    }

    float c_reg = 0.0f;                  // cell state (redundant x8 per unit)
    if (tid < HSZ) hsb[0][tid] = 0.0f;

    // loader wave preload: x[0] -> LDS, x[1] -> xr
    const float* xb = x + (size_t)b * (TSZ * ISZ);
    const int lload = tid - 448;         // valid for tid >= 448
    float xr = 0.0f;
    if (tid >= 448) {
        xs[0][lload] = xb[lload];
        xr = xb[ISZ + lload];
    }
    __syncthreads();

    for (int t = 0; t < TSZ; t += 2) {
        LSTM_STEP(0, t)
        LSTM_STEP(1, t + 1)
    }
    // last step (t=999, CUR=1) wrote h_final into hsb[0]; its barrier makes
    // it visible -- no extra sync needed.

    if (tid < 2) {
        float acc = b_out[tid];
        const float* wo = W_out + tid * HSZ;
        #pragma unroll
        for (int j = 0; j < HSZ; ++j) acc += hsb[0][j] * wo[j];
        out[b * 2 + tid] = acc;
    }
}

extern "C" void kernel_launch(void* const* d_in, const int* in_sizes, int n_in,
                              void* d_out, int out_size, void* d_ws, size_t ws_size,
                              hipStream_t stream) {
    const float* x     = (const float*)d_in[0];
    const float* W_ih  = (const float*)d_in[1];
    const float* W_hh  = (const float*)d_in[2];
    const float* b_ih  = (const float*)d_in[3];
    const float* b_hh  = (const float*)d_in[4];
    const float* W_out = (const float*)d_in[5];
    const float* b_out = (const float*)d_in[6];
    float* out = (float*)d_out;

    const int B = in_sizes[0] / (TSZ * ISZ);   // 512
    hipLaunchKernelGGL(lstm_fused, dim3(B), dim3(512), 0, stream,
                       x, W_ih, W_hh, b_ih, b_hh, W_out, b_out, out);
}

// Round 2
// 815.208 us; speedup vs baseline: 1.2331x; 1.2331x over previous
//
#include <hip/hip_runtime.h>
#include <math.h>

// LSTM: B=512, T=1000, I=64, H=50, gates 4H=200 (torch order i,f,g,o).
// One block per batch row, 512 threads = 8 waves, ONE s_barrier per step.
//
//   waves 0-3 (tid<256, active tid<200): CONSUMERS. lane -> (u=tid>>2, g=tid&3),
//       gate k = g*50+u. Holds W_hh row k (25 f32x2) in VGPRs. Per step:
//       acc = xg[t][k] (LDS ring, produced 2 steps ago) + h . whh  (dual-acc
//       pkfma chain), activation, quad_perm DPP exchange (the 4 gates of unit
//       u sit in lanes 4u..4u+3), c update (redundant x4), lane g==0 writes h.
//   waves 4-7 (P=tid-256): P<200: PRODUCERS. Holds W_ih row P (32 f32x2).
//       Per step computes xg[t+2] = bias + x[t+2] . wih from the x LDS ring
//       into the xg LDS ring (off the serial path; 2-barrier pipeline slack).
//   P in [224,256): LOADERS. Depth-2 global prefetch of x rows (f32x2/lane)
//       across raw s_barriers -- HBM latency (~2 steps in flight) never lands
//       on the critical path.
//
// Weight arrays are UNIONED (wreg[32]) -- no lane needs both W_ih and W_hh,
// keeping the frame < 128 VGPRs at __launch_bounds__(512,4) so the allocator
// does not demote weights to AGPRs (round-1 failure: VGPR_Count=48 + accvgpr
// moves). All cross-lane exchange is DPP (VALU latency), not ds_swizzle.

#define HSZ 50
#define ISZ 64
#define TSZ 1000

typedef float f32x2 __attribute__((ext_vector_type(2)));

__device__ __forceinline__ void pkfma(f32x2& acc, f32x2 a, f32x2 b) {
    asm("v_pk_fma_f32 %0, %1, %2, %0" : "+v"(acc) : "v"(a), "v"(b));
}

// quad_perm DPP: xor1 = [1,0,3,2] = 0xB1 ; xor2 = [2,3,0,1] = 0x4E
__device__ __forceinline__ float dpp_xor1(float v) {
    return __int_as_float(__builtin_amdgcn_update_dpp(
        0, __float_as_int(v), 0xB1, 0xF, 0xF, true));
}
__device__ __forceinline__ float dpp_xor2(float v) {
    return __int_as_float(__builtin_amdgcn_update_dpp(
        0, __float_as_int(v), 0x4E, 0xF, 0xF, true));
}

// One step. OFF in {0,1,2,3} is compile-time; s = t+OFF, t % 4 == 0, so
// s%4 == OFF and s%2 == OFF&1 -- all LDS ring indices fold to constants.
#define LSTM_STEP(t, OFF, XR)                                                  \
  {                                                                            \
    if (tid < 256) {                                                           \
      if (tid < 200) {                                                         \
        float acc0 = xgbuf[(OFF) & 3][k];                                      \
        f32x2 accA; accA.x = acc0; accA.y = 0.0f;                              \
        f32x2 accB; accB.x = 0.0f; accB.y = 0.0f;                              \
        const float4* h4 = (const float4*)(&hbuf[(OFF) & 1][0]);               \
        _Pragma("unroll")                                                      \
        for (int j = 0; j < 12; ++j) {                                         \
          float4 v = h4[j];                                                    \
          f32x2 lo = {v.x, v.y};                                               \
          f32x2 hi = {v.z, v.w};                                               \
          pkfma(accA, lo, wreg[2 * j]);                                        \
          pkfma(accB, hi, wreg[2 * j + 1]);                                    \
        }                                                                      \
        f32x2 t2 = *(const f32x2*)(&hbuf[(OFF) & 1][48]);                      \
        pkfma(accA, t2, wreg[24]);                                             \
        float acc = (accA.x + accB.x) + (accA.y + accB.y);                     \
        float arg = isg ? (acc + acc) : acc;                                   \
        float e = __expf(-arg);                                                \
        float sg = __fdividef(1.0f, 1.0f + e);                                 \
        float a = isg ? (sg + sg - 1.0f) : sg;                                 \
        float bb = dpp_xor1(a);                                                \
        float cv = dpp_xor2(a);                                                \
        float dv = dpp_xor2(bb);                                               \
        float xlo = b0 ? bb : a,  xhi = b0 ? a : bb;                           \
        float ylo = b0 ? dv : cv, yhi = b0 ? cv : dv;                          \
        float ig = b1 ? ylo : xlo, fg = b1 ? yhi : xhi;                        \
        float gg = b1 ? xlo : ylo, og = b1 ? xhi : yhi;                        \
        c_reg = fg * c_reg + ig * gg;                                          \
        float ep = __expf(c_reg + c_reg);                                      \
        float th = 1.0f - __fdividef(2.0f, 1.0f + ep);                         \
        if ((tid & 3) == 0) hbuf[((OFF) + 1) & 1][u] = og * th;                \
      }                                                                        \
    } else if (P < 200) {                                                      \
      if ((t) + (OFF) + 2 < TSZ) {                                             \
        f32x2 accA; accA.x = bias; accA.y = 0.0f;                              \
        f32x2 accB; accB.x = 0.0f; accB.y = 0.0f;                              \
        const float4* x4 = (const float4*)(&xbuf[((OFF) + 2) & 3][0]);         \
        _Pragma("unroll")                                                      \
        for (int i = 0; i < 16; ++i) {                                         \
          float4 v = x4[i];                                                    \
          f32x2 lo = {v.x, v.y};                                               \
          f32x2 hi = {v.z, v.w};                                               \
          pkfma(accA, lo, wreg[2 * i]);                                        \
          pkfma(accB, hi, wreg[2 * i + 1]);                                    \
        }                                                                      \
        xgbuf[((OFF) + 2) & 3][P] = (accA.x + accB.x) + (accA.y + accB.y);     \
      }                                                                        \
    } else if (ll >= 0) {                                                      \
      if ((t) + (OFF) + 3 < TSZ)                                               \
        *(f32x2*)(&xbuf[((OFF) + 3) & 3][2 * ll]) = XR;                        \
      if ((t) + (OFF) + 5 < TSZ)                                               \
        XR = *(const f32x2*)(xb + (size_t)((t) + (OFF) + 5) * ISZ + 2 * ll);   \
    }                                                                          \
    asm volatile("s_waitcnt lgkmcnt(0)" ::: "memory");                         \
    __builtin_amdgcn_s_barrier();                                              \
    __builtin_amdgcn_sched_barrier(0);                                         \
  }

__global__ __launch_bounds__(512, 4) void lstm_fused(
    const float* __restrict__ x,      // [B, T, I]
    const float* __restrict__ W_ih,   // [4H, I]
    const float* __restrict__ W_hh,   // [4H, H]
    const float* __restrict__ b_ih,   // [4H]
    const float* __restrict__ b_hh,   // [4H]
    const float* __restrict__ W_out,  // [2, H]
    const float* __restrict__ b_out,  // [2]
    float* __restrict__ out)          // [B, 2]
{
    const int b   = blockIdx.x;
    const int tid = threadIdx.x;

    __shared__ __align__(16) float xbuf[4][ISZ];    // x ring      (1 KiB)
    __shared__ __align__(16) float xgbuf[4][200];   // xg ring     (3.2 KiB)
    __shared__ __align__(16) float hbuf[2][56];     // h ping-pong

    // consumer coords (valid tid<200)
    const int g = tid & 3;            // gate 0=i 1=f 2=g 3=o
    const int u = tid >> 2;           // unit
    const int k = g * HSZ + u;        // gate row in [0,200)
    const bool isg = (g == 2);
    const bool b0  = (g & 1) != 0;
    const bool b1  = (g & 2) != 0;

    // producer / loader coords
    const int P  = tid - 256;         // producer gate row (tid>=256)
    const int ll = P - 224;           // loader lane 0..31 (P in [224,256))

    // UNIONED weight registers: consumers load W_hh row (25 pairs),
    // producers load W_ih row (32 pairs). No lane needs both.
    f32x2 wreg[32];
    float bias  = 0.0f;
    float c_reg = 0.0f;
    f32x2 xr0; xr0.x = 0.0f; xr0.y = 0.0f;
    f32x2 xr1; xr1.x = 0.0f; xr1.y = 0.0f;

    const float* xb = x + (size_t)b * (TSZ * ISZ);

    if (tid < 200) {
        const float* wh = W_hh + k * HSZ;
        #pragma unroll
        for (int j = 0; j < 25; ++j) wreg[j] = *(const f32x2*)(wh + 2 * j);
    } else if (tid >= 256 && P < 200) {
        const float* wi = W_ih + P * ISZ;
        #pragma unroll
        for (int i = 0; i < 32; ++i) wreg[i] = *(const f32x2*)(wi + 2 * i);
        bias = b_ih[P] + b_hh[P];
    } else if (ll >= 0) {
        // loaders: stage x[0..2] into the ring, prefetch x[3],x[4] into regs
        #pragma unroll
        for (int n = 0; n < 3; ++n) {
            f32x2 v = *(const f32x2*)(xb + n * ISZ + 2 * ll);
            *(f32x2*)(&xbuf[n][2 * ll]) = v;
        }
        xr0 = *(const f32x2*)(xb + 3 * ISZ + 2 * ll);
        xr1 = *(const f32x2*)(xb + 4 * ISZ + 2 * ll);
    }
    if (tid < HSZ) { hbuf[0][tid] = 0.0f; hbuf[1][tid] = 0.0f; }
    __syncthreads();

    // producer prologue: xg[0], xg[1]
    if (tid >= 256 && P < 200) {
        #pragma unroll
        for (int n = 0; n < 2; ++n) {
            f32x2 accA; accA.x = bias; accA.y = 0.0f;
            f32x2 accB; accB.x = 0.0f; accB.y = 0.0f;
            const float4* x4 = (const float4*)(&xbuf[n][0]);
            #pragma unroll
            for (int i = 0; i < 16; ++i) {
                float4 v = x4[i];
                f32x2 lo = {v.x, v.y};
                f32x2 hi = {v.z, v.w};
                pkfma(accA, lo, wreg[2 * i]);
                pkfma(accB, hi, wreg[2 * i + 1]);
            }
            xgbuf[n][P] = (accA.x + accB.x) + (accA.y + accB.y);
        }
    }
    __syncthreads();

    for (int t = 0; t < TSZ; t += 4) {
        LSTM_STEP(t, 0, xr0)
        LSTM_STEP(t, 1, xr1)
        LSTM_STEP(t, 2, xr0)
        LSTM_STEP(t, 3, xr1)
    }
    // last step (s=999, OFF=3) wrote h_final into hbuf[0]; its lgkmcnt(0)
    // + s_barrier makes it visible.

    if (tid < 2) {
        float acc = b_out[tid];
        const float* wo = W_out + tid * HSZ;
        #pragma unroll
        for (int j = 0; j < HSZ; ++j) acc += hbuf[0][j] * wo[j];
        out[b * 2 + tid] = acc;
    }
}

extern "C" void kernel_launch(void* const* d_in, const int* in_sizes, int n_in,
                              void* d_out, int out_size, void* d_ws, size_t ws_size,
                              hipStream_t stream) {
    const float* x     = (const float*)d_in[0];
    const float* W_ih  = (const float*)d_in[1];
    const float* W_hh  = (const float*)d_in[2];
    const float* b_ih  = (const float*)d_in[3];
    const float* b_hh  = (const float*)d_in[4];
    const float* W_out = (const float*)d_in[5];
    const float* b_out = (const float*)d_in[6];
    float* out = (float*)d_out;

    const int B = in_sizes[0] / (TSZ * ISZ);   // 512
    hipLaunchKernelGGL(lstm_fused, dim3(B), dim3(512), 0, stream,
                       x, W_ih, W_hh, b_ih, b_hh, W_out, b_out, out);
}

// Round 3
// 788.460 us; speedup vs baseline: 1.2749x; 1.0339x over previous
//
#include <hip/hip_runtime.h>
#include <math.h>

// LSTM: B=512, T=1000, I=64, H=50, gates 4H=200 (torch order i,f,g,o).
// One block per batch row, 512 threads = 8 waves, ONE s_barrier per step.
//
//   waves 0-3 (tid<256, active tid<200): CONSUMERS. lane -> (u=tid>>2, g=tid&3),
//       gate k = g*50+u. Holds W_hh row k (25 f32x2) in registers. Per step:
//       acc = xg[t][k] (LDS ring, produced 2 steps ago) + h . whh, activation,
//       quad_perm DPP exchange (4 gates of unit u in lanes 4u..4u+3), c update,
//       lane g==0 writes h.
//   waves 4-7 (P=tid-256): P<200: PRODUCERS. Holds W_ih row P (32 f32x2).
//       Per step computes xg[t+2] = bias + x[t+2] . wih from the x LDS ring
//       into the xg LDS ring (2-barrier pipeline slack, off the serial path).
//   P in [224,256): LOADERS. Depth-2 global prefetch of x rows (f32x2/lane)
//       across raw s_barriers -- HBM latency never lands on the critical path.
//
// ROUND-3 CHANGE: no inline asm. R1/R2 used `v_pk_fma_f32` inline asm with
// "v" constraints; rocprof showed VGPR_Count=52 (weights demoted out of arch
// VGPRs) and ~3x VALU issue bloat (v_accvgpr_read + v_mov repacks around
// every FMA). Plain C on f32x2 lets -ffp-contract emit pk-fma/fmac with the
// allocator free to place weights, and LDS pairs feed FMAs as subregisters.

#define HSZ 50
#define ISZ 64
#define TSZ 1000

typedef float f32x2 __attribute__((ext_vector_type(2)));

// quad_perm DPP: xor1 = [1,0,3,2] = 0xB1 ; xor2 = [2,3,0,1] = 0x4E
__device__ __forceinline__ float dpp_xor1(float v) {
    return __int_as_float(__builtin_amdgcn_update_dpp(
        0, __float_as_int(v), 0xB1, 0xF, 0xF, true));
}
__device__ __forceinline__ float dpp_xor2(float v) {
    return __int_as_float(__builtin_amdgcn_update_dpp(
        0, __float_as_int(v), 0x4E, 0xF, 0xF, true));
}

// One step. OFF in {0,1,2,3} is compile-time; s = t+OFF, t % 4 == 0, so
// s%4 == OFF and s%2 == OFF&1 -- all LDS ring indices fold to constants.
#define LSTM_STEP(t, OFF, XR)                                                  \
  {                                                                            \
    if (tid < 256) {                                                           \
      if (tid < 200) {                                                         \
        float acc0 = xgbuf[(OFF) & 3][k];                                      \
        const f32x2* h2 = (const f32x2*)(&hbuf[(OFF) & 1][0]);                 \
        f32x2 accA; accA.x = acc0; accA.y = 0.0f;                              \
        f32x2 accB; accB.x = 0.0f; accB.y = 0.0f;                              \
        _Pragma("unroll")                                                      \
        for (int j = 0; j < 12; ++j) {                                         \
          accA += h2[2 * j]     * wreg[2 * j];                                 \
          accB += h2[2 * j + 1] * wreg[2 * j + 1];                             \
        }                                                                      \
        accA += h2[24] * wreg[24];       /* h[48],h[49] */                     \
        float acc = (accA.x + accB.x) + (accA.y + accB.y);                     \
        float arg = isg ? (acc + acc) : acc;                                   \
        float e = __expf(-arg);                                                \
        float sg = __fdividef(1.0f, 1.0f + e);                                 \
        float a = isg ? (sg + sg - 1.0f) : sg;                                 \
        float bb = dpp_xor1(a);                                                \
        float cv = dpp_xor2(a);                                                \
        float dv = dpp_xor2(bb);                                               \
        float xlo = b0 ? bb : a,  xhi = b0 ? a : bb;                           \
        float ylo = b0 ? dv : cv, yhi = b0 ? cv : dv;                          \
        float ig = b1 ? ylo : xlo, fg = b1 ? yhi : xhi;                        \
        float gg = b1 ? xlo : ylo, og = b1 ? xhi : yhi;                        \
        c_reg = fg * c_reg + ig * gg;                                          \
        float ep = __expf(c_reg + c_reg);                                      \
        float th = 1.0f - __fdividef(2.0f, 1.0f + ep);                         \
        if ((tid & 3) == 0) hbuf[((OFF) + 1) & 1][u] = og * th;                \
      }                                                                        \
    } else if (P < 200) {                                                      \
      if ((t) + (OFF) + 2 < TSZ) {                                             \
        const f32x2* x2 = (const f32x2*)(&xbuf[((OFF) + 2) & 3][0]);           \
        f32x2 accA; accA.x = bias; accA.y = 0.0f;                              \
        f32x2 accB; accB.x = 0.0f; accB.y = 0.0f;                              \
        _Pragma("unroll")                                                      \
        for (int i = 0; i < 16; ++i) {                                         \
          accA += x2[2 * i]     * wreg[2 * i];                                 \
          accB += x2[2 * i + 1] * wreg[2 * i + 1];                             \
        }                                                                      \
        xgbuf[((OFF) + 2) & 3][P] = (accA.x + accB.x) + (accA.y + accB.y);     \
      }                                                                        \
    } else if (ll >= 0) {                                                      \
      if ((t) + (OFF) + 3 < TSZ)                                               \
        *(f32x2*)(&xbuf[((OFF) + 3) & 3][2 * ll]) = XR;                        \
      if ((t) + (OFF) + 5 < TSZ)                                               \
        XR = *(const f32x2*)(xb + (size_t)((t) + (OFF) + 5) * ISZ + 2 * ll);   \
    }                                                                          \
    asm volatile("s_waitcnt lgkmcnt(0)" ::: "memory");                         \
    __builtin_amdgcn_s_barrier();                                              \
    __builtin_amdgcn_sched_barrier(0);                                         \
  }

__global__ __launch_bounds__(512, 4) void lstm_fused(
    const float* __restrict__ x,      // [B, T, I]
    const float* __restrict__ W_ih,   // [4H, I]
    const float* __restrict__ W_hh,   // [4H, H]
    const float* __restrict__ b_ih,   // [4H]
    const float* __restrict__ b_hh,   // [4H]
    const float* __restrict__ W_out,  // [2, H]
    const float* __restrict__ b_out,  // [2]
    float* __restrict__ out)          // [B, 2]
{
    const int b   = blockIdx.x;
    const int tid = threadIdx.x;

    __shared__ __align__(16) float xbuf[4][ISZ];    // x ring      (1 KiB)
    __shared__ __align__(16) float xgbuf[4][200];   // xg ring     (3.2 KiB)
    __shared__ __align__(16) float hbuf[2][56];     // h ping-pong

    // consumer coords (valid tid<200)
    const int g = tid & 3;            // gate 0=i 1=f 2=g 3=o
    const int u = tid >> 2;           // unit
    const int k = g * HSZ + u;        // gate row in [0,200)
    const bool isg = (g == 2);
    const bool b0  = (g & 1) != 0;
    const bool b1  = (g & 2) != 0;

    // producer / loader coords
    const int P  = tid - 256;         // producer gate row (tid>=256)
    const int ll = P - 224;           // loader lane 0..31 (P in [224,256))

    // UNIONED weight registers: consumers load W_hh row (25 pairs),
    // producers load W_ih row (32 pairs). No lane needs both.
    f32x2 wreg[32];
    float bias  = 0.0f;
    float c_reg = 0.0f;
    f32x2 xr0; xr0.x = 0.0f; xr0.y = 0.0f;
    f32x2 xr1; xr1.x = 0.0f; xr1.y = 0.0f;

    const float* xb = x + (size_t)b * (TSZ * ISZ);

    if (tid < 200) {
        const float* wh = W_hh + k * HSZ;
        #pragma unroll
        for (int j = 0; j < 25; ++j) wreg[j] = *(const f32x2*)(wh + 2 * j);
    } else if (tid >= 256 && P < 200) {
        const float* wi = W_ih + P * ISZ;
        #pragma unroll
        for (int i = 0; i < 32; ++i) wreg[i] = *(const f32x2*)(wi + 2 * i);
        bias = b_ih[P] + b_hh[P];
    } else if (ll >= 0) {
        // loaders: stage x[0..2] into the ring, prefetch x[3],x[4] into regs
        #pragma unroll
        for (int n = 0; n < 3; ++n) {
            f32x2 v = *(const f32x2*)(xb + n * ISZ + 2 * ll);
            *(f32x2*)(&xbuf[n][2 * ll]) = v;
        }
        xr0 = *(const f32x2*)(xb + 3 * ISZ + 2 * ll);
        xr1 = *(const f32x2*)(xb + 4 * ISZ + 2 * ll);
    }
    if (tid < HSZ) { hbuf[0][tid] = 0.0f; hbuf[1][tid] = 0.0f; }
    __syncthreads();

    // producer prologue: xg[0], xg[1]
    if (tid >= 256 && P < 200) {
        #pragma unroll
        for (int n = 0; n < 2; ++n) {
            const f32x2* x2 = (const f32x2*)(&xbuf[n][0]);
            f32x2 accA; accA.x = bias; accA.y = 0.0f;
            f32x2 accB; accB.x = 0.0f; accB.y = 0.0f;
            #pragma unroll
            for (int i = 0; i < 16; ++i) {
                accA += x2[2 * i]     * wreg[2 * i];
                accB += x2[2 * i + 1] * wreg[2 * i + 1];
            }
            xgbuf[n][P] = (accA.x + accB.x) + (accA.y + accB.y);
        }
    }
    __syncthreads();

    for (int t = 0; t < TSZ; t += 4) {
        LSTM_STEP(t, 0, xr0)
        LSTM_STEP(t, 1, xr1)
        LSTM_STEP(t, 2, xr0)
        LSTM_STEP(t, 3, xr1)
    }
    // last step (s=999, OFF=3) wrote h_final into hbuf[0]; its lgkmcnt(0)
    // + s_barrier makes it visible.

    if (tid < 2) {
        float acc = b_out[tid];
        const float* wo = W_out + tid * HSZ;
        #pragma unroll
        for (int j = 0; j < HSZ; ++j) acc += hbuf[0][j] * wo[j];
        out[b * 2 + tid] = acc;
    }
}

extern "C" void kernel_launch(void* const* d_in, const int* in_sizes, int n_in,
                              void* d_out, int out_size, void* d_ws, size_t ws_size,
                              hipStream_t stream) {
    const float* x     = (const float*)d_in[0];
    const float* W_ih  = (const float*)d_in[1];
    const float* W_hh  = (const float*)d_in[2];
    const float* b_ih  = (const float*)d_in[3];
    const float* b_hh  = (const float*)d_in[4];
    const float* W_out = (const float*)d_in[5];
    const float* b_out = (const float*)d_in[6];
    float* out = (float*)d_out;

    const int B = in_sizes[0] / (TSZ * ISZ);   // 512
    hipLaunchKernelGGL(lstm_fused, dim3(B), dim3(512), 0, stream,
                       x, W_ih, W_hh, b_ih, b_hh, W_out, b_out, out);
}

// Round 4
// 771.240 us; speedup vs baseline: 1.3034x; 1.0223x over previous
//
#include <hip/hip_runtime.h>
#include <math.h>

// LSTM: B=512, T=1000, I=64, H=50, gates 4H=200 (torch order i,f,g,o).
//
// ROUND-4 STRUCTURE: one block = TWO batch rows, 512 threads, grid B/2=256
// (1 block/CU, 2 waves/SIMD, each wave fully loaded -> issue-bound floor).
//   row  = tid>>8, rtid = tid&255.
//   rtid < 200  : MERGED worker. lane -> (u=rtid>>2, g=rtid&3), gate k=g*50+u.
//       Holds BOTH W_hh row k (25 f32x2) and W_ih row k (32 f32x2) in regs
//       (cap 256 VGPRs via __launch_bounds__(512,2)).
//       Per step s: gates = xg_reg + h . whh  (xg produced by THIS lane two
//       steps ago -> register double-buffer xgA/xgB, no xg LDS ring at all);
//       activation via per-lane consts (no cndmask); directed quad_perm DPP
//       (own/xor1/xor2/reverse) -> cell update; lane g==0 writes h to LDS.
//       Then produces xg for s+2 from the x LDS ring (off the serial path).
//   rtid >= 224 : LOADER (32 lanes). Depth-2 global prefetch of x rows into
//       the 4-deep x LDS ring across raw lgkmcnt-only barriers.
// ONE s_barrier per step. The two rows' waves share each SIMD and cover each
// other's latency gaps.

#define HSZ 50
#define ISZ 64
#define TSZ 1000

typedef float f32x2 __attribute__((ext_vector_type(2)));

// quad_perm DPP helpers
__device__ __forceinline__ float dpp_xor1(float v) {  // [1,0,3,2]
    return __int_as_float(__builtin_amdgcn_update_dpp(
        0, __float_as_int(v), 0xB1, 0xF, 0xF, true));
}
__device__ __forceinline__ float dpp_xor2(float v) {  // [2,3,0,1]
    return __int_as_float(__builtin_amdgcn_update_dpp(
        0, __float_as_int(v), 0x4E, 0xF, 0xF, true));
}
__device__ __forceinline__ float dpp_rev(float v) {   // [3,2,1,0]
    return __int_as_float(__builtin_amdgcn_update_dpp(
        0, __float_as_int(v), 0x1B, 0xF, 0xF, true));
}

// One step, s = t+OFF, OFF compile-time in {0,1,2,3}; t%4==0.
// XR: loader's in-flight f32x2; XG: this lane's xg register for parity OFF&1.
#define LSTM_STEP(t, OFF, XR, XG)                                              \
  {                                                                            \
    if (rtid < 200) {                                                          \
      /* ---- consume: gates for step s ---- */                                \
      f32x2 accA; accA.x = XG; accA.y = 0.0f;                                  \
      f32x2 accB; accB.x = 0.0f; accB.y = 0.0f;                                \
      const float4* h4 = (const float4*)(&hbuf[row][(OFF) & 1][0]);            \
      _Pragma("unroll")                                                        \
      for (int j = 0; j < 12; ++j) {                                           \
        float4 v = h4[j];                                                      \
        f32x2 lo; lo.x = v.x; lo.y = v.y;                                      \
        f32x2 hi; hi.x = v.z; hi.y = v.w;                                      \
        accA += lo * whh[2 * j];                                               \
        accB += hi * whh[2 * j + 1];                                           \
      }                                                                        \
      { f32x2 tl = *(const f32x2*)(&hbuf[row][(OFF) & 1][48]);                 \
        accA += tl * whh[24]; }                                                \
      float acc = (accA.x + accB.x) + (accA.y + accB.y);                       \
      float e  = __expf(-(acc * gmul));                                        \
      float sg = __builtin_amdgcn_rcpf(1.0f + e);                              \
      float a  = __builtin_fmaf(sg, gma, gmb);   /* sigmoid or tanh */         \
      float fg = dpp_xor1(a);   /* on g==0 lane: f from lane+1 */              \
      float gg = dpp_xor2(a);   /*               g from lane+2 */              \
      float og = dpp_rev(a);    /*               o from lane+3 */              \
      c_reg = __builtin_fmaf(fg, c_reg, a * gg);  /* a == i on g==0 lane */    \
      float ep = __expf(2.0f * c_reg);                                         \
      float rr = __builtin_amdgcn_rcpf(1.0f + ep);                             \
      float hv = __builtin_fmaf(-2.0f * og, rr, og); /* og * tanh(c) */        \
      if ((rtid & 3) == 0) hbuf[row][((OFF) + 1) & 1][u] = hv;                 \
      /* ---- produce: xg for step s+2 (x staged >=1 barrier ago) ---- */      \
      if ((t) + (OFF) + 2 < TSZ) {                                             \
        f32x2 pA; pA.x = bias; pA.y = 0.0f;                                    \
        f32x2 pB; pB.x = 0.0f; pB.y = 0.0f;                                    \
        const float4* x4 = (const float4*)(&xbuf[row][((OFF) + 2) & 3][0]);    \
        _Pragma("unroll")                                                      \
        for (int i = 0; i < 16; ++i) {                                         \
          float4 v = x4[i];                                                    \
          f32x2 lo; lo.x = v.x; lo.y = v.y;                                    \
          f32x2 hi; hi.x = v.z; hi.y = v.w;                                    \
          pA += lo * wih[2 * i];                                               \
          pB += hi * wih[2 * i + 1];                                           \
        }                                                                      \
        XG = (pA.x + pB.x) + (pA.y + pB.y);                                    \
      }                                                                        \
    } else if (rtid >= 224) {                                                  \
      if ((t) + (OFF) + 3 < TSZ)                                               \
        *(f32x2*)(&xbuf[row][((OFF) + 3) & 3][2 * ll]) = XR;                   \
      if ((t) + (OFF) + 5 < TSZ)                                               \
        XR = *(const f32x2*)(xrow + (size_t)((t) + (OFF) + 5) * ISZ + 2 * ll); \
    }                                                                          \
    /* drain LDS only; loader's global load stays in flight */                 \
    asm volatile("s_waitcnt lgkmcnt(0)" ::: "memory");                         \
    __builtin_amdgcn_s_barrier();                                              \
    __builtin_amdgcn_sched_barrier(0);                                         \
  }

__global__ __launch_bounds__(512, 2) void lstm_fused(
    const float* __restrict__ x,      // [B, T, I]
    const float* __restrict__ W_ih,   // [4H, I]
    const float* __restrict__ W_hh,   // [4H, H]
    const float* __restrict__ b_ih,   // [4H]
    const float* __restrict__ b_hh,   // [4H]
    const float* __restrict__ W_out,  // [2, H]
    const float* __restrict__ b_out,  // [2]
    float* __restrict__ out)          // [B, 2]
{
    const int bb   = blockIdx.x;
    const int tid  = threadIdx.x;
    const int row  = tid >> 8;        // 0 or 1: which batch row of this block
    const int rtid = tid & 255;

    __shared__ __align__(16) float xbuf[2][4][ISZ];   // x ring per row (2 KiB)
    __shared__ __align__(16) float hbuf[2][2][56];    // h ping-pong per row

    // worker coords (valid rtid<200)
    const int g = rtid & 3;           // 0=i 1=f 2=g 3=o
    const int u = rtid >> 2;          // unit
    const int k = g * HSZ + u;        // gate row in [0,200)
    // per-lane activation constants: sigmoid lanes (1,1,0), tanh lane (2,2,-1)
    const float gmul = (g == 2) ? 2.0f : 1.0f;
    const float gma  = (g == 2) ? 2.0f : 1.0f;
    const float gmb  = (g == 2) ? -1.0f : 0.0f;

    const int ll = rtid - 224;        // loader lane 0..31 (rtid>=224)

    const float* xrow = x + (size_t)(2 * bb + row) * (TSZ * ISZ);

    // per-lane weights (both matrices; cap=256 VGPRs at launch_bounds(512,2))
    f32x2 whh[25];
    f32x2 wih[32];
    float bias  = 0.0f;
    float c_reg = 0.0f;
    float xgA = 0.0f, xgB = 0.0f;     // xg register double-buffer
    f32x2 xr0; xr0.x = 0.0f; xr0.y = 0.0f;
    f32x2 xr1; xr1.x = 0.0f; xr1.y = 0.0f;

    if (rtid < 200) {
        const float* wh = W_hh + k * HSZ;
        #pragma unroll
        for (int j = 0; j < 25; ++j) whh[j] = *(const f32x2*)(wh + 2 * j);
        const float* wi = W_ih + k * ISZ;
        #pragma unroll
        for (int i = 0; i < 32; ++i) wih[i] = *(const f32x2*)(wi + 2 * i);
        bias = b_ih[k] + b_hh[k];
    } else if (ll >= 0) {
        // stage x[0..2] into ring slots 0..2; prefetch x[3],x[4] into regs
        #pragma unroll
        for (int n = 0; n < 3; ++n) {
            f32x2 v = *(const f32x2*)(xrow + n * ISZ + 2 * ll);
            *(f32x2*)(&xbuf[row][n][2 * ll]) = v;
        }
        xr0 = *(const f32x2*)(xrow + 3 * ISZ + 2 * ll);
        xr1 = *(const f32x2*)(xrow + 4 * ISZ + 2 * ll);
    }
    if (rtid < 56) { hbuf[row][0][rtid] = 0.0f; hbuf[row][1][rtid] = 0.0f; }
    __syncthreads();

    // xg prologue (registers only): xgA for s=0 from x[0], xgB for s=1 from x[1]
    if (rtid < 200) {
        #pragma unroll
        for (int n = 0; n < 2; ++n) {
            f32x2 pA; pA.x = bias; pA.y = 0.0f;
            f32x2 pB; pB.x = 0.0f; pB.y = 0.0f;
            const float4* x4 = (const float4*)(&xbuf[row][n][0]);
            #pragma unroll
            for (int i = 0; i < 16; ++i) {
                float4 v = x4[i];
                f32x2 lo; lo.x = v.x; lo.y = v.y;
                f32x2 hi; hi.x = v.z; hi.y = v.w;
                pA += lo * wih[2 * i];
                pB += hi * wih[2 * i + 1];
            }
            float r = (pA.x + pB.x) + (pA.y + pB.y);
            if (n == 0) xgA = r; else xgB = r;
        }
    }

    for (int t = 0; t < TSZ; t += 4) {
        LSTM_STEP(t, 0, xr0, xgA)
        LSTM_STEP(t, 1, xr1, xgB)
        LSTM_STEP(t, 2, xr0, xgA)
        LSTM_STEP(t, 3, xr1, xgB)
    }
    // last step (s=999, OFF=3) wrote h_final into hbuf[row][0]; its
    // lgkmcnt(0) + s_barrier makes it visible.

    if (rtid < 2) {
        float acc = b_out[rtid];
        const float* wo = W_out + rtid * HSZ;
        #pragma unroll
        for (int j = 0; j < HSZ; ++j) acc += hbuf[row][0][j] * wo[j];
        out[(2 * bb + row) * 2 + rtid] = acc;
    }
}

extern "C" void kernel_launch(void* const* d_in, const int* in_sizes, int n_in,
                              void* d_out, int out_size, void* d_ws, size_t ws_size,
                              hipStream_t stream) {
    const float* x     = (const float*)d_in[0];
    const float* W_ih  = (const float*)d_in[1];
    const float* W_hh  = (const float*)d_in[2];
    const float* b_ih  = (const float*)d_in[3];
    const float* b_hh  = (const float*)d_in[4];
    const float* W_out = (const float*)d_in[5];
    const float* b_out = (const float*)d_in[6];
    float* out = (float*)d_out;

    const int B = in_sizes[0] / (TSZ * ISZ);   // 512
    hipLaunchKernelGGL(lstm_fused, dim3(B / 2), dim3(512), 0, stream,
                       x, W_ih, W_hh, b_ih, b_hh, W_out, b_out, out);
}